// Round 19
// baseline (172.597 us; speedup 1.0000x reference)
//
#include <hip/hip_runtime.h>
#include <cstdint>
#include <cstddef>

#define HH 128
#define WW 128
#define LL 16384   // HH*WW
#define BL 32768   // B*LL

typedef float  f32x4  __attribute__((ext_vector_type(4)));
typedef __fp16 h2     __attribute__((ext_vector_type(2)));
typedef __fp16 h8     __attribute__((ext_vector_type(8)));

union U32H { unsigned u; h2 h; };

static __device__ __forceinline__ float fdot2(h2 a, h2 b, float c) {
  return __builtin_amdgcn_fdot2(a, b, c, false);
}
static __device__ __forceinline__ unsigned pkh2(float a, float b) {
  h2 h = __builtin_amdgcn_cvt_pkrtz(a, b);
  U32H t; t.h = h; return t.u;
}
static __device__ __forceinline__ h2 bcasth(float a) {
  return __builtin_amdgcn_cvt_pkrtz(a, a);
}
static __device__ __forceinline__ unsigned short f2h(float x) {
  union { __fp16 h; unsigned short u; } c; c.h = (__fp16)x; return c.u;
}

#define LOADH8(dst, ptr) { \
  uint4 _a = *(const uint4*)(ptr); uint4 _b = *(const uint4*)((ptr)+8); U32H _t; \
  _t.u=_a.x; dst[0]=_t.h; _t.u=_a.y; dst[1]=_t.h; _t.u=_a.z; dst[2]=_t.h; _t.u=_a.w; dst[3]=_t.h; \
  _t.u=_b.x; dst[4]=_t.h; _t.u=_b.y; dst[5]=_t.h; _t.u=_b.z; dst[6]=_t.h; _t.u=_b.w; dst[7]=_t.h; }

// ---- k0: fold proj into fusion weight (fp16 B^T [64][800], kk = t*32+c); cast w1/w2 --
__global__ __launch_bounds__(256) void k_combine(
    const float* __restrict__ proj_w, const float* __restrict__ proj_b,
    const float* __restrict__ fw, const float* __restrict__ fb,
    const float* __restrict__ w1, const float* __restrict__ w2,
    unsigned short* __restrict__ wctT, float* __restrict__ bc,
    unsigned short* __restrict__ w1h, unsigned short* __restrict__ w2h)
{
  if (blockIdx.x == 200) {
    int o = threadIdx.x;
    if (o < 64) {
      float acc = proj_b[o];
      for (int m = 0; m < 64; ++m) acc = fmaf(proj_w[o*64+m], fb[m], acc);
      bc[o] = acc;
    }
    return;
  }
  if (blockIdx.x == 201) {
    for (int i = threadIdx.x; i < 8192; i += 256) w1h[i] = f2h(w1[i]);
    return;
  }
  if (blockIdx.x == 202) {
    for (int i = threadIdx.x; i < 8192; i += 256) w2h[i] = f2h(w2[i]);
    return;
  }
  int gid = blockIdx.x * 256 + threadIdx.x;   // 0..51199 = o*800 + kk
  int o  = gid / 800;
  int kk = gid - o * 800;
  int c  = kk & 31;        // de-interleaved channel (nh*16+d)
  int t  = kk >> 5;        // window position 0..24
  int in = c * 25 + t;     // fusion weight flat index
  float acc = 0.f;
  for (int m = 0; m < 64; ++m) acc = fmaf(proj_w[o*64+m], fw[m*800+in], acc);
  wctT[gid] = f2h(acc);
}

// ---- k1: LayerNorm + QKV, fp16 out, de-interleaved (c' = nh*16 + d); 3-way split ----
__global__ __launch_bounds__(128) void k_ln_qkv(
    const float* __restrict__ x, const float* __restrict__ qkv_w,
    const float* __restrict__ qkv_b, const float* __restrict__ n1w,
    const float* __restrict__ n1b, unsigned short* __restrict__ qo,
    unsigned short* __restrict__ ko, unsigned short* __restrict__ vo)
{
  __shared__ float sW[32*32];
  __shared__ float sB[32];
  __shared__ float sNw[32], sNb[32];
  int p = blockIdx.y;                         // 0=q 1=k 2=v
  for (int i = threadIdx.x; i < 32*32; i += 128) sW[i] = qkv_w[p*1024 + i];
  if (threadIdx.x < 32) {
    sB[threadIdx.x]  = qkv_b[p*32 + threadIdx.x];
    sNw[threadIdx.x] = n1w[threadIdx.x];
    sNb[threadIdx.x] = n1b[threadIdx.x];
  }
  __syncthreads();
  int gid = blockIdx.x * 128 + threadIdx.x;   // 0..BL-1
  int b = gid >> 14, l = gid & (LL - 1);
  const float* xp = x + (size_t)b * 32 * LL + l;
  float xv[32];
  float mean = 0.f;
  #pragma unroll
  for (int c = 0; c < 32; ++c) { xv[c] = xp[(size_t)c * LL]; mean += xv[c]; }
  mean *= 0.03125f;
  float var = 0.f;
  #pragma unroll
  for (int c = 0; c < 32; ++c) { float d = xv[c] - mean; var = fmaf(d, d, var); }
  float rs = rsqrtf(var * 0.03125f + 1e-5f);
  #pragma unroll
  for (int c = 0; c < 32; ++c) xv[c] = (xv[c] - mean) * rs * sNw[c] + sNb[c];
  float ao[32];
  #pragma unroll
  for (int o = 0; o < 32; ++o) {
    const float* wr = &sW[o * 32];
    float acc = sB[o];
    #pragma unroll
    for (int c = 0; c < 32; ++c) acc = fmaf(xv[c], wr[c], acc);
    ao[(o & 1) * 16 + (o >> 1)] = acc;        // de-interleave heads
  }
  unsigned short* op = (p == 0 ? qo : p == 1 ? ko : vo) + (size_t)gid * 32;
  #pragma unroll
  for (int e = 0; e < 4; ++e) {
    uint4 pk4;
    pk4.x = pkh2(ao[e*8+0], ao[e*8+1]);
    pk4.y = pkh2(ao[e*8+2], ao[e*8+3]);
    pk4.z = pkh2(ao[e*8+4], ao[e*8+5]);
    pk4.w = pkh2(ao[e*8+6], ao[e*8+7]);
    *(uint4*)(op + e*8) = pk4;
  }
}

// ---- k2: TH=2 tile (16 locs), parity-scheduled fused L+S rows, Q from L2 ------------
#define TH 2
#define TW 8
#define NPOS 72   // 6x12 halo
#define KVSTR 24  // per-head fp16 row stride in ushorts (48B)
#define OSTRU 524 // sO row stride (ushorts): 512 kk + 12 pad

// CLS: class parity of the slot's locations. SLOW: full mask logic (boundary blocks).
template<int CLS, bool SLOW>
static __device__ __forceinline__ void attn_ls(
    int tqL, int tqS, bool wL, bool wS, int nh,
    int h0, int w0, int ly, int lx, int b,
    const unsigned short* __restrict__ qi,
    int posb, int sOrow, int klbase,
    const unsigned short* __restrict__ sK,
    const unsigned short* __restrict__ sV, unsigned short* __restrict__ sO,
    const float* __restrict__ sRT, const float* __restrict__ sPar)
{
  const int nhb = nh * 72;
  int iqL = tqL / 5, jqL = tqL - iqL * 5;
  int iqS = tqS / 5, jqS = tqS - iqS * 5;
  int hqL = h0 + ly + iqL - 2, wqL = w0 + lx + jqL - 2;
  int hqS = h0 + ly + iqS - 2, wqS = w0 + lx + jqS - 2;
  h2 qL[8], qS[8];
  float parqL = 0.f, parqS = 0.f;
  if (SLOW) {
    bool vL = ((unsigned)hqL < HH) && ((unsigned)wqL < WW);
    bool vS = ((unsigned)hqS < HH) && ((unsigned)wqS < WW);
    parqL = (vL && (((hqL + wqL) & 1) == 1)) ? 1.f : 0.f;
    parqS = (vS && (((hqS + wqS) & 1) == 1)) ? 1.f : 0.f;
    if (vL) {
      LOADH8(qL, qi + ((size_t)((b<<14)+(hqL<<7)+wqL))*32 + nh*16);
    } else {
      for (int u = 0; u < 8; ++u) qL[u] = (h2)(__fp16)0.f;
    }
    if (vS) {
      LOADH8(qS, qi + ((size_t)((b<<14)+(hqS<<7)+wqS))*32 + nh*16);
    } else {
      for (int u = 0; u < 8; ++u) qS[u] = (h2)(__fp16)0.f;
    }
  } else {
    LOADH8(qL, qi + ((size_t)((b<<14)+(hqL<<7)+wqL))*32 + nh*16);
    LOADH8(qS, qi + ((size_t)((b<<14)+(hqS<<7)+wqS))*32 + nh*16);
  }
  const int bbL = (iqL * 9 + jqL) * 2 + 80 + nh;
  const int bbS = (iqS * 9 + jqS) * 2 + 80 + nh;
  float sumL = 0.f, sumS = 0.f;
  h2 ooL[8], ooS[8];
  #pragma unroll
  for (int e = 0; e < 8; ++e) { ooL[e] = (h2)(__fp16)0.f; ooS[e] = (h2)(__fp16)0.f; }

  auto body = [&](int ik, int jk, bool doS) {
    int pk = posb + ik * 12 + jk;
    int bL = bbL - ik * 18 - 2 * jk;
    int bS = bbS - ik * 18 - 2 * jk;
    h2 kh[8]; LOADH8(kh, &sK[(nhb + pk) * KVSTR]);
    h2 vh[8]; LOADH8(vh, &sV[(nhb + pk) * KVSTR]);
    float mk = 0.f;
    if (SLOW) { float park = sPar[pk]; mk = (park == 1.f) ? 0.f : -100.f; }
    {
      float a = 0.f;
      #pragma unroll
      for (int u = 0; u < 8; ++u) a = fdot2(qL[u], kh[u], a);
      float e = SLOW ? __expf(fmaf(parqL, mk, fmaf(a, 0.25f, sRT[bL])))
                     : __expf(fmaf(a, 0.25f, sRT[bL]));
      sumL += e;
      h2 eh = bcasth(e);
      #pragma unroll
      for (int u = 0; u < 8; ++u) ooL[u] = eh * vh[u] + ooL[u];
    }
    if (doS) {
      float a = 0.f;
      #pragma unroll
      for (int u = 0; u < 8; ++u) a = fdot2(qS[u], kh[u], a);
      float e = SLOW ? __expf(fmaf(parqS, mk, fmaf(a, 0.25f, sRT[bS])))
                     : __expf(fmaf(a, 0.25f, sRT[bS]));
      sumS += e;
      h2 eh = bcasth(e);
      #pragma unroll
      for (int u = 0; u < 8; ++u) ooS[u] = eh * vh[u] + ooS[u];
    }
  };

  if (SLOW) {
    #pragma unroll 1
    for (int ik = 0; ik < 5; ++ik) {
      body(ik,0,true); body(ik,1,true); body(ik,2,true); body(ik,3,true); body(ik,4,true);
    }
  } else {
    // FULLY UNROLLED: 25 straight-line bodies so the scheduler can pipeline LDS loads
    #pragma unroll
    for (int ik = 0; ik < 5; ++ik) {
      const bool odd = (ik & 1) != 0;
      // S active when (ik+jk) parity matches class
      if (CLS == 0) {
        if (!odd) { body(ik,0,false); body(ik,1,true);  body(ik,2,false); body(ik,3,true);  body(ik,4,false); }
        else      { body(ik,0,true);  body(ik,1,false); body(ik,2,true);  body(ik,3,false); body(ik,4,true); }
      } else {
        if (!odd) { body(ik,0,true);  body(ik,1,false); body(ik,2,true);  body(ik,3,false); body(ik,4,true); }
        else      { body(ik,0,false); body(ik,1,true);  body(ik,2,false); body(ik,3,true);  body(ik,4,false); }
      }
    }
  }
  if (wL) {
    h2 ih = bcasth(1.f / sumL);
    int kl = (tqL - klbase) * 32 + nh * 16;
    union { h2 h[8]; uint4 u4[2]; } R;
    #pragma unroll
    for (int u = 0; u < 8; ++u) R.h[u] = ooL[u] * ih;
    *(uint4*)&sO[sOrow * OSTRU + kl] = R.u4[0];
    *(uint4*)&sO[sOrow * OSTRU + kl + 8] = R.u4[1];
  }
  if (wS) {
    h2 ih = bcasth(1.f / sumS);
    int kl = (tqS - klbase) * 32 + nh * 16;
    union { h2 h[8]; uint4 u4[2]; } R;
    #pragma unroll
    for (int u = 0; u < 8; ++u) R.h[u] = ooS[u] * ih;
    *(uint4*)&sO[sOrow * OSTRU + kl] = R.u4[0];
    *(uint4*)&sO[sOrow * OSTRU + kl + 8] = R.u4[1];
  }
}

__global__ __launch_bounds__(256, 4) void k_attn(
    const unsigned short* __restrict__ qi, const unsigned short* __restrict__ ki,
    const unsigned short* __restrict__ vi, const float* __restrict__ rel_table,
    const unsigned short* __restrict__ wctT, const float* __restrict__ bc,
    float* __restrict__ y2)
{
  __shared__ __align__(16) unsigned short sK[144*KVSTR]; // 6912 B
  __shared__ __align__(16) unsigned short sV[144*KVSTR]; // 6912 B
  __shared__ __align__(16) unsigned short sO[16*OSTRU];  // 16768 B
  __shared__ float sRT[162];
  __shared__ float sPar[NPOS];
  // total ~31.5 KB -> 4 blocks/CU

  int tid = threadIdx.x;
  int lane = tid & 63, wv = tid >> 6;
  int b  = blockIdx.z;
  int h0 = blockIdx.y * TH, w0 = blockIdx.x * TW;
  bool fastb = (blockIdx.y >= 1) && (blockIdx.y <= 62) && (blockIdx.x >= 1) && (blockIdx.x <= 14);

  for (int i = tid; i < 162; i += 256) sRT[i] = rel_table[i];
  if (tid < NPOS) {
    int ph = tid / 12, pw = tid - ph * 12;
    int h2v = h0 + ph - 2, w2v = w0 + pw - 2;
    bool valid = ((unsigned)h2v < HH) && ((unsigned)w2v < WW);
    sPar[tid] = (valid && (((h2v + w2v) & 1) == 1)) ? 1.f : 0.f;
  }
  // halo staging: K,V: 2 arrays x 72 pos x 2 nh x 2 half-chunks(16B) = 576 units
  for (int idx = tid; idx < 576; idx += 256) {
    int arr = idx / 288;                  // 0=K, 1=V
    int rem = idx - arr * 288;
    int pos = rem >> 2, q4 = rem & 3;
    int nh = q4 >> 1, half = q4 & 1;
    int ph = pos / 12, pw = pos - ph * 12;
    int h2v = h0 + ph - 2, w2v = w0 + pw - 2;
    uint4 val = make_uint4(0u, 0u, 0u, 0u);
    if (((unsigned)h2v < HH) && ((unsigned)w2v < WW)) {
      const unsigned short* src = (arr == 0 ? ki : vi)
                       + ((size_t)((b << 14) + (h2v << 7) + w2v)) * 32 + nh * 16 + half * 8;
      val = *(const uint4*)src;
    }
    unsigned short* dp = (arr == 0 ? sK : sV) + (nh * 72 + pos) * KVSTR + half * 8;
    *(uint4*)dp = val;
  }
  __syncthreads();

  f32x4 acc = {0.f, 0.f, 0.f, 0.f};
  int ocol = wv * 16 + (lane & 15);

  // slot geometry: 8-lane groups; cls = wave parity class; r8 = row-slot
  int cls = wv & 1;                         // wave-uniform
  int nh  = wv >> 1;
  int l8  = lane & 7;
  int r8  = lane >> 3;                      // 0..7
  int ly  = l8 >> 2;
  int lx  = 2 * (l8 & 3) + ((cls + ly) & 1);
  int posb  = ly * 12 + lx;
  int sOrow = cls * 8 + l8;

  // ---- phase 0: rows tq 0..15 (L rows: class-long; S rows: class-short)
  if (fastb) {
    if (cls == 0) attn_ls<0,false>(2*r8,   2*r8+1, true, true, nh, h0,w0,ly,lx,b,qi, posb, sOrow, 0, sK, sV, sO, sRT, sPar);
    else          attn_ls<1,false>(2*r8+1, 2*r8,   true, true, nh, h0,w0,ly,lx,b,qi, posb, sOrow, 0, sK, sV, sO, sRT, sPar);
  } else {
    int tl = (cls == 0) ? 2*r8 : 2*r8+1;
    int ts = (cls == 0) ? 2*r8+1 : 2*r8;
    attn_ls<0,true>(tl, ts, true, true, nh, h0,w0,ly,lx,b,qi, posb, sOrow, 0, sK, sV, sO, sRT, sPar);
  }
  __syncthreads();
  {
    const unsigned short* bcol = wctT + (size_t)ocol * 800 + (lane >> 4) * 8;
    for (int kt = 0; kt < 16; ++kt) {
      h8 bfrag = *(const h8*)(bcol + kt * 32);
      h8 afrag = *(const h8*)&sO[(lane & 15)*OSTRU + kt*32 + (lane >> 4)*8];
      acc = __builtin_amdgcn_mfma_f32_16x16x32_f16(afrag, bfrag, acc, 0, 0, 0);
    }
  }
  __syncthreads();

  // ---- phase 1: rows tq 16..24
  {
    int tqL, tqS; bool wL, wS;
    if (cls == 0) {
      tqL = (r8 < 5) ? 16 + 2*r8 : 16; wL = (r8 < 5);
      tqS = (r8 < 4) ? 17 + 2*r8 : 17; wS = (r8 < 4);
    } else {
      tqL = (r8 < 4) ? 17 + 2*r8 : 17; wL = (r8 < 4);
      tqS = (r8 < 5) ? 16 + 2*r8 : 16; wS = (r8 < 5);
    }
    if (fastb) {
      if (cls == 0) attn_ls<0,false>(tqL, tqS, wL, wS, nh, h0,w0,ly,lx,b,qi, posb, sOrow, 16, sK, sV, sO, sRT, sPar);
      else          attn_ls<1,false>(tqL, tqS, wL, wS, nh, h0,w0,ly,lx,b,qi, posb, sOrow, 16, sK, sV, sO, sRT, sPar);
    } else {
      attn_ls<0,true>(tqL, tqS, wL, wS, nh, h0,w0,ly,lx,b,qi, posb, sOrow, 16, sK, sV, sO, sRT, sPar);
    }
  }
  __syncthreads();
  {
    const unsigned short* bcol = wctT + (size_t)ocol * 800 + 512 + (lane >> 4) * 8;
    for (int kt = 0; kt < 9; ++kt) {
      h8 bfrag = *(const h8*)(bcol + kt * 32);
      h8 afrag = *(const h8*)&sO[(lane & 15)*OSTRU + kt*32 + (lane >> 4)*8];
      acc = __builtin_amdgcn_mfma_f32_16x16x32_f16(afrag, bfrag, acc, 0, 0, 0);
    }
  }
  __syncthreads();

  // epilogue: class-major row -> (ly,lx) remap
  float bco = bc[ocol];
  #pragma unroll
  for (int r2 = 0; r2 < 4; ++r2) {
    int r = (lane >> 4) * 4 + r2;           // 0..15
    int cls2 = r >> 3, i8 = r & 7;
    int ly2 = i8 >> 2, lx2 = 2 * (i8 & 3) + ((cls2 + ly2) & 1);
    int gid = (b << 14) + ((h0 + ly2) << 7) + (w0 + lx2);
    y2[(size_t)gid * 64 + ocol] = acc[r2] + bco;
  }
}

// ---- k3: LN + MLP via MFMA f16 (GELU exact), M0=32 tiles (1024 blocks) --------------
__global__ __launch_bounds__(256) void k_mlp(
    const float* __restrict__ y2, const float* __restrict__ n2w,
    const float* __restrict__ n2b, const unsigned short* __restrict__ w1h,
    const float* __restrict__ b1, const unsigned short* __restrict__ w2h,
    const float* __restrict__ b2, float* __restrict__ out)
{
  __shared__ __align__(16) unsigned short sA[32*72];   // 4608 B
  __shared__ __align__(16) unsigned short sH[32*136];  // 8704 B
  int tid = threadIdx.x;
  int lane = tid & 63, wv = tid >> 6;
  int m0 = blockIdx.x * 32;
  // ---- LN: 8 threads per row (32 rows)
  {
    int r = tid >> 3, qd = tid & 7;
    const float* yp = y2 + (size_t)(m0 + r) * 64 + qd * 8;
    float xv[8];
    float s = 0.f;
    #pragma unroll
    for (int e = 0; e < 2; ++e) {
      float4 t4 = *(const float4*)(yp + e*4);
      xv[4*e] = t4.x; xv[4*e+1] = t4.y; xv[4*e+2] = t4.z; xv[4*e+3] = t4.w;
      s += t4.x + t4.y + t4.z + t4.w;
    }
    s += __shfl_xor(s, 1);
    s += __shfl_xor(s, 2);
    s += __shfl_xor(s, 4);
    float mean = s * (1.f/64.f);
    float v = 0.f;
    #pragma unroll
    for (int e = 0; e < 8; ++e) { float d = xv[e] - mean; v = fmaf(d, d, v); }
    v += __shfl_xor(v, 1);
    v += __shfl_xor(v, 2);
    v += __shfl_xor(v, 4);
    float rs = rsqrtf(v * (1.f/64.f) + 1e-5f);
    #pragma unroll
    for (int u = 0; u < 4; ++u) {
      int c0 = qd*8 + 2*u;
      float h0v = (xv[2*u]   - mean) * rs * n2w[c0]   + n2b[c0];
      float h1v = (xv[2*u+1] - mean) * rs * n2w[c0+1] + n2b[c0+1];
      *(unsigned*)&sA[r*72 + c0] = pkh2(h0v, h1v);
    }
  }
  __syncthreads();
  // ---- GEMM1: [32x64] x W1^T -> [32x128], n-slice 32 per wave
  f32x4 acc1[2][2];
  #pragma unroll
  for (int mt = 0; mt < 2; ++mt)
    #pragma unroll
    for (int nt = 0; nt < 2; ++nt) acc1[mt][nt] = (f32x4){0.f,0.f,0.f,0.f};
  #pragma unroll
  for (int kt = 0; kt < 2; ++kt) {
    #pragma unroll
    for (int nt = 0; nt < 2; ++nt) {
      int ncol = wv*32 + nt*16 + (lane & 15);
      h8 bfrag = *(const h8*)(w1h + ncol*64 + kt*32 + (lane >> 4)*8);
      #pragma unroll
      for (int mt = 0; mt < 2; ++mt) {
        h8 afrag = *(const h8*)&sA[(mt*16 + (lane & 15))*72 + kt*32 + (lane >> 4)*8];
        acc1[mt][nt] = __builtin_amdgcn_mfma_f32_16x16x32_f16(afrag, bfrag, acc1[mt][nt], 0, 0, 0);
      }
    }
  }
  // ---- bias + exact GELU -> sH (fp16)
  #pragma unroll
  for (int nt = 0; nt < 2; ++nt) {
    int ncol = wv*32 + nt*16 + (lane & 15);
    float b1v = b1[ncol];
    #pragma unroll
    for (int mt = 0; mt < 2; ++mt) {
      #pragma unroll
      for (int r2 = 0; r2 < 4; ++r2) {
        int mrow = mt*16 + (lane >> 4)*4 + r2;
        float h = acc1[mt][nt][r2] + b1v;
        float g = 0.5f * h * (1.f + erff(h * 0.70710678118f));
        sH[mrow*136 + ncol] = f2h(g);
      }
    }
  }
  __syncthreads();
  // ---- GEMM2: [32x128] x W2^T -> [32x64], n-slice 16 per wave
  f32x4 acc2[2];
  #pragma unroll
  for (int mt = 0; mt < 2; ++mt) acc2[mt] = (f32x4){0.f,0.f,0.f,0.f};
  int ocol = wv*16 + (lane & 15);
  #pragma unroll
  for (int kt = 0; kt < 4; ++kt) {
    h8 bfrag = *(const h8*)(w2h + ocol*128 + kt*32 + (lane >> 4)*8);
    #pragma unroll
    for (int mt = 0; mt < 2; ++mt) {
      h8 afrag = *(const h8*)&sH[(mt*16 + (lane & 15))*136 + kt*32 + (lane >> 4)*8];
      acc2[mt] = __builtin_amdgcn_mfma_f32_16x16x32_f16(afrag, bfrag, acc2[mt], 0, 0, 0);
    }
  }
  // ---- residual + bias + transpose store
  float b2v = b2[ocol];
  int bb = m0 >> 14;
  #pragma unroll
  for (int mt = 0; mt < 2; ++mt) {
    int mrow = mt*16 + (lane >> 4)*4;
    int l = m0 + mrow;
    const float* yp = y2 + (size_t)l * 64 + ocol;
    float4 o4;
    o4.x = yp[0]   + acc2[mt][0] + b2v;
    o4.y = yp[64]  + acc2[mt][1] + b2v;
    o4.z = yp[128] + acc2[mt][2] + b2v;
    o4.w = yp[192] + acc2[mt][3] + b2v;
    *(float4*)&out[(size_t)bb * 64 * LL + (size_t)ocol * LL + (l - (bb << 14))] = o4;
  }
}

extern "C" void kernel_launch(void* const* d_in, const int* in_sizes, int n_in,
                              void* d_out, int out_size, void* d_ws, size_t ws_size,
                              hipStream_t stream) {
  const float* x         = (const float*)d_in[0];
  const float* qkv_w     = (const float*)d_in[1];
  const float* qkv_b     = (const float*)d_in[2];
  const float* rel_table = (const float*)d_in[3];
  const float* n1w       = (const float*)d_in[4];
  const float* n1b       = (const float*)d_in[5];
  const float* n2w       = (const float*)d_in[6];
  const float* n2b       = (const float*)d_in[7];
  const float* proj_w    = (const float*)d_in[8];
  const float* proj_b    = (const float*)d_in[9];
  const float* fw        = (const float*)d_in[10];
  const float* fb        = (const float*)d_in[11];
  const float* w1        = (const float*)d_in[12];
  const float* b1        = (const float*)d_in[13];
  const float* w2        = (const float*)d_in[14];
  const float* b2        = (const float*)d_in[15];

  char* ws = (char*)d_ws;
  unsigned short* q    = (unsigned short*)(ws);                    // BL*32 fp16 = 2MB
  unsigned short* k    = (unsigned short*)(ws + 2097152);          // 2MB
  unsigned short* v    = (unsigned short*)(ws + 4194304);          // 2MB
  float*          y2   = (float*)(ws + 6291456);                   // BL*64 f32 = 8MB
  unsigned short* wctT = (unsigned short*)(ws + 14680064);         // 64*800 fp16
  float*          bc   = (float*)(ws + 14782464);                  // 64 f32
  unsigned short* w1h  = (unsigned short*)(ws + 14782720);         // 8192 fp16
  unsigned short* w2h  = (unsigned short*)(ws + 14799104);         // 8192 fp16
  float* out = (float*)d_out;

  k_combine<<<203, 256, 0, stream>>>(proj_w, proj_b, fw, fb, w1, w2, wctT, bc, w1h, w2h);
  k_ln_qkv<<<dim3(BL/128, 3), 128, 0, stream>>>(x, qkv_w, qkv_b, n1w, n1b, q, k, v);
  k_attn<<<dim3(WW/TW, HH/TH, 2), 256, 0, stream>>>(q, k, v, rel_table, wctT, bc, y2);
  k_mlp<<<BL/32, 256, 0, stream>>>(y2, n2w, n2b, w1h, b1, w2h, b2, out);
}

// Round 20
// 85.972 us; speedup vs baseline: 2.0076x; 2.0076x over previous
//
#include <hip/hip_runtime.h>
#include <cstdint>
#include <cstddef>

#define HH 128
#define WW 128
#define LL 16384   // HH*WW
#define BL 32768   // B*LL

typedef float  f32x4  __attribute__((ext_vector_type(4)));
typedef __fp16 h2     __attribute__((ext_vector_type(2)));
typedef __fp16 h8     __attribute__((ext_vector_type(8)));

union U32H { unsigned u; h2 h; };

static __device__ __forceinline__ float fdot2(h2 a, h2 b, float c) {
  return __builtin_amdgcn_fdot2(a, b, c, false);
}
static __device__ __forceinline__ unsigned pkh2(float a, float b) {
  h2 h = __builtin_amdgcn_cvt_pkrtz(a, b);
  U32H t; t.h = h; return t.u;
}
static __device__ __forceinline__ h2 bcasth(float a) {
  return __builtin_amdgcn_cvt_pkrtz(a, a);
}
static __device__ __forceinline__ unsigned short f2h(float x) {
  union { __fp16 h; unsigned short u; } c; c.h = (__fp16)x; return c.u;
}

#define LOADH8(dst, ptr) { \
  uint4 _a = *(const uint4*)(ptr); uint4 _b = *(const uint4*)((ptr)+8); U32H _t; \
  _t.u=_a.x; dst[0]=_t.h; _t.u=_a.y; dst[1]=_t.h; _t.u=_a.z; dst[2]=_t.h; _t.u=_a.w; dst[3]=_t.h; \
  _t.u=_b.x; dst[4]=_t.h; _t.u=_b.y; dst[5]=_t.h; _t.u=_b.z; dst[6]=_t.h; _t.u=_b.w; dst[7]=_t.h; }

// ---- k0: fold proj into fusion weight (fp16 B^T [64][800], kk = t*32+c); cast w1/w2 --
__global__ __launch_bounds__(256) void k_combine(
    const float* __restrict__ proj_w, const float* __restrict__ proj_b,
    const float* __restrict__ fw, const float* __restrict__ fb,
    const float* __restrict__ w1, const float* __restrict__ w2,
    unsigned short* __restrict__ wctT, float* __restrict__ bc,
    unsigned short* __restrict__ w1h, unsigned short* __restrict__ w2h)
{
  if (blockIdx.x == 200) {
    int o = threadIdx.x;
    if (o < 64) {
      float acc = proj_b[o];
      for (int m = 0; m < 64; ++m) acc = fmaf(proj_w[o*64+m], fb[m], acc);
      bc[o] = acc;
    }
    return;
  }
  if (blockIdx.x == 201) {
    for (int i = threadIdx.x; i < 8192; i += 256) w1h[i] = f2h(w1[i]);
    return;
  }
  if (blockIdx.x == 202) {
    for (int i = threadIdx.x; i < 8192; i += 256) w2h[i] = f2h(w2[i]);
    return;
  }
  int gid = blockIdx.x * 256 + threadIdx.x;   // 0..51199 = o*800 + kk
  int o  = gid / 800;
  int kk = gid - o * 800;
  int c  = kk & 31;        // de-interleaved channel (nh*16+d)
  int t  = kk >> 5;        // window position 0..24
  int in = c * 25 + t;     // fusion weight flat index
  float acc = 0.f;
  for (int m = 0; m < 64; ++m) acc = fmaf(proj_w[o*64+m], fw[m*800+in], acc);
  wctT[gid] = f2h(acc);
}

// ---- k1: LayerNorm + QKV, fp16 out, de-interleaved (c' = nh*16 + d); 3-way split ----
__global__ __launch_bounds__(128) void k_ln_qkv(
    const float* __restrict__ x, const float* __restrict__ qkv_w,
    const float* __restrict__ qkv_b, const float* __restrict__ n1w,
    const float* __restrict__ n1b, unsigned short* __restrict__ qo,
    unsigned short* __restrict__ ko, unsigned short* __restrict__ vo)
{
  __shared__ float sW[32*32];
  __shared__ float sB[32];
  __shared__ float sNw[32], sNb[32];
  int p = blockIdx.y;                         // 0=q 1=k 2=v
  for (int i = threadIdx.x; i < 32*32; i += 128) sW[i] = qkv_w[p*1024 + i];
  if (threadIdx.x < 32) {
    sB[threadIdx.x]  = qkv_b[p*32 + threadIdx.x];
    sNw[threadIdx.x] = n1w[threadIdx.x];
    sNb[threadIdx.x] = n1b[threadIdx.x];
  }
  __syncthreads();
  int gid = blockIdx.x * 128 + threadIdx.x;   // 0..BL-1
  int b = gid >> 14, l = gid & (LL - 1);
  const float* xp = x + (size_t)b * 32 * LL + l;
  float xv[32];
  float mean = 0.f;
  #pragma unroll
  for (int c = 0; c < 32; ++c) { xv[c] = xp[(size_t)c * LL]; mean += xv[c]; }
  mean *= 0.03125f;
  float var = 0.f;
  #pragma unroll
  for (int c = 0; c < 32; ++c) { float d = xv[c] - mean; var = fmaf(d, d, var); }
  float rs = rsqrtf(var * 0.03125f + 1e-5f);
  #pragma unroll
  for (int c = 0; c < 32; ++c) xv[c] = (xv[c] - mean) * rs * sNw[c] + sNb[c];
  float ao[32];
  #pragma unroll
  for (int o = 0; o < 32; ++o) {
    const float* wr = &sW[o * 32];
    float acc = sB[o];
    #pragma unroll
    for (int c = 0; c < 32; ++c) acc = fmaf(xv[c], wr[c], acc);
    ao[(o & 1) * 16 + (o >> 1)] = acc;        // de-interleave heads
  }
  unsigned short* op = (p == 0 ? qo : p == 1 ? ko : vo) + (size_t)gid * 32;
  #pragma unroll
  for (int e = 0; e < 4; ++e) {
    uint4 pk4;
    pk4.x = pkh2(ao[e*8+0], ao[e*8+1]);
    pk4.y = pkh2(ao[e*8+2], ao[e*8+3]);
    pk4.z = pkh2(ao[e*8+4], ao[e*8+5]);
    pk4.w = pkh2(ao[e*8+6], ao[e*8+7]);
    *(uint4*)(op + e*8) = pk4;
  }
}

// ---- k2: TH=2 tile (16 locs), parity-scheduled fused L+S rows, Q from L2 ------------
#define TH 2
#define TW 8
#define NPOS 72   // 6x12 halo
#define KVSTR 24  // per-head fp16 row stride in ushorts (48B)
#define OSTRU 524 // sO row stride (ushorts): 512 kk + 12 pad

// CLS: class parity of the slot's locations. SLOW: full mask logic (boundary blocks).
template<int CLS, bool SLOW>
static __device__ __forceinline__ void attn_ls(
    int tqL, int tqS, bool wL, bool wS, int nh,
    int h0, int w0, int ly, int lx, int b,
    const unsigned short* __restrict__ qi,
    int posb, int sOrow, int klbase,
    const unsigned short* __restrict__ sK,
    const unsigned short* __restrict__ sV, unsigned short* __restrict__ sO,
    const float* __restrict__ sRT, const float* __restrict__ sPar)
{
  const int nhb = nh * 72;
  int iqL = tqL / 5, jqL = tqL - iqL * 5;
  int iqS = tqS / 5, jqS = tqS - iqS * 5;
  int hqL = h0 + ly + iqL - 2, wqL = w0 + lx + jqL - 2;
  int hqS = h0 + ly + iqS - 2, wqS = w0 + lx + jqS - 2;
  h2 qL[8], qS[8];
  float parqL = 0.f, parqS = 0.f;
  if (SLOW) {
    bool vL = ((unsigned)hqL < HH) && ((unsigned)wqL < WW);
    bool vS = ((unsigned)hqS < HH) && ((unsigned)wqS < WW);
    parqL = (vL && (((hqL + wqL) & 1) == 1)) ? 1.f : 0.f;
    parqS = (vS && (((hqS + wqS) & 1) == 1)) ? 1.f : 0.f;
    if (vL) {
      LOADH8(qL, qi + ((size_t)((b<<14)+(hqL<<7)+wqL))*32 + nh*16);
    } else {
      for (int u = 0; u < 8; ++u) qL[u] = (h2)(__fp16)0.f;
    }
    if (vS) {
      LOADH8(qS, qi + ((size_t)((b<<14)+(hqS<<7)+wqS))*32 + nh*16);
    } else {
      for (int u = 0; u < 8; ++u) qS[u] = (h2)(__fp16)0.f;
    }
  } else {
    LOADH8(qL, qi + ((size_t)((b<<14)+(hqL<<7)+wqL))*32 + nh*16);
    LOADH8(qS, qi + ((size_t)((b<<14)+(hqS<<7)+wqS))*32 + nh*16);
  }
  const int bbL = (iqL * 9 + jqL) * 2 + 80 + nh;
  const int bbS = (iqS * 9 + jqS) * 2 + 80 + nh;
  float sumL = 0.f, sumS = 0.f;
  h2 ooL[8], ooS[8];
  #pragma unroll
  for (int e = 0; e < 8; ++e) { ooL[e] = (h2)(__fp16)0.f; ooS[e] = (h2)(__fp16)0.f; }
  #pragma unroll 1
  for (int ik = 0; ik < 5; ++ik) {
    int pkrow = posb + ik * 12;
    int bL = bbL - ik * 18, bS = bbS - ik * 18;
    auto body = [&](int jk, bool doS) {
      int pk = pkrow + jk;
      h2 kh[8]; LOADH8(kh, &sK[(nhb + pk) * KVSTR]);
      h2 vh[8]; LOADH8(vh, &sV[(nhb + pk) * KVSTR]);
      float mk = 0.f;
      if (SLOW) { float park = sPar[pk]; mk = (park == 1.f) ? 0.f : -100.f; }
      {
        float a = 0.f;
        #pragma unroll
        for (int u = 0; u < 8; ++u) a = fdot2(qL[u], kh[u], a);
        float e = SLOW ? __expf(fmaf(parqL, mk, fmaf(a, 0.25f, sRT[bL - 2*jk])))
                       : __expf(fmaf(a, 0.25f, sRT[bL - 2*jk]));
        sumL += e;
        h2 eh = bcasth(e);
        #pragma unroll
        for (int u = 0; u < 8; ++u) ooL[u] = eh * vh[u] + ooL[u];
      }
      if (doS) {
        float a = 0.f;
        #pragma unroll
        for (int u = 0; u < 8; ++u) a = fdot2(qS[u], kh[u], a);
        float e = SLOW ? __expf(fmaf(parqS, mk, fmaf(a, 0.25f, sRT[bS - 2*jk])))
                       : __expf(fmaf(a, 0.25f, sRT[bS - 2*jk]));
        sumS += e;
        h2 eh = bcasth(e);
        #pragma unroll
        for (int u = 0; u < 8; ++u) ooS[u] = eh * vh[u] + ooS[u];
      }
    };
    if (SLOW) {
      body(0,true); body(1,true); body(2,true); body(3,true); body(4,true);
    } else if (CLS == 0) {      // S active when (ik+jk) odd
      if ((ik & 1) == 0) { body(0,false); body(1,true);  body(2,false); body(3,true);  body(4,false); }
      else               { body(0,true);  body(1,false); body(2,true);  body(3,false); body(4,true); }
    } else {                    // S active when (ik+jk) even
      if ((ik & 1) == 0) { body(0,true);  body(1,false); body(2,true);  body(3,false); body(4,true); }
      else               { body(0,false); body(1,true);  body(2,false); body(3,true);  body(4,false); }
    }
  }
  if (wL) {
    h2 ih = bcasth(1.f / sumL);
    int kl = (tqL - klbase) * 32 + nh * 16;
    union { h2 h[8]; uint4 u4[2]; } R;
    #pragma unroll
    for (int u = 0; u < 8; ++u) R.h[u] = ooL[u] * ih;
    *(uint4*)&sO[sOrow * OSTRU + kl] = R.u4[0];
    *(uint4*)&sO[sOrow * OSTRU + kl + 8] = R.u4[1];
  }
  if (wS) {
    h2 ih = bcasth(1.f / sumS);
    int kl = (tqS - klbase) * 32 + nh * 16;
    union { h2 h[8]; uint4 u4[2]; } R;
    #pragma unroll
    for (int u = 0; u < 8; ++u) R.h[u] = ooS[u] * ih;
    *(uint4*)&sO[sOrow * OSTRU + kl] = R.u4[0];
    *(uint4*)&sO[sOrow * OSTRU + kl + 8] = R.u4[1];
  }
}

__global__ __launch_bounds__(256, 4) void k_attn(
    const unsigned short* __restrict__ qi, const unsigned short* __restrict__ ki,
    const unsigned short* __restrict__ vi, const float* __restrict__ rel_table,
    const unsigned short* __restrict__ wctT, const float* __restrict__ bc,
    float* __restrict__ y2)
{
  __shared__ __align__(16) unsigned short sK[144*KVSTR]; // 6912 B
  __shared__ __align__(16) unsigned short sV[144*KVSTR]; // 6912 B
  __shared__ __align__(16) unsigned short sO[16*OSTRU];  // 16768 B
  __shared__ float sRT[162];
  __shared__ float sPar[NPOS];
  // total ~31.5 KB -> 4 blocks/CU

  int tid = threadIdx.x;
  int lane = tid & 63, wv = tid >> 6;
  int b  = blockIdx.z;
  int h0 = blockIdx.y * TH, w0 = blockIdx.x * TW;
  bool fastb = (blockIdx.y >= 1) && (blockIdx.y <= 62) && (blockIdx.x >= 1) && (blockIdx.x <= 14);

  for (int i = tid; i < 162; i += 256) sRT[i] = rel_table[i];
  if (tid < NPOS) {
    int ph = tid / 12, pw = tid - ph * 12;
    int h2v = h0 + ph - 2, w2v = w0 + pw - 2;
    bool valid = ((unsigned)h2v < HH) && ((unsigned)w2v < WW);
    sPar[tid] = (valid && (((h2v + w2v) & 1) == 1)) ? 1.f : 0.f;
  }
  // halo staging: K,V: 2 arrays x 72 pos x 2 nh x 2 half-chunks(16B) = 576 units
  for (int idx = tid; idx < 576; idx += 256) {
    int arr = idx / 288;                  // 0=K, 1=V
    int rem = idx - arr * 288;
    int pos = rem >> 2, q4 = rem & 3;
    int nh = q4 >> 1, half = q4 & 1;
    int ph = pos / 12, pw = pos - ph * 12;
    int h2v = h0 + ph - 2, w2v = w0 + pw - 2;
    uint4 val = make_uint4(0u, 0u, 0u, 0u);
    if (((unsigned)h2v < HH) && ((unsigned)w2v < WW)) {
      const unsigned short* src = (arr == 0 ? ki : vi)
                       + ((size_t)((b << 14) + (h2v << 7) + w2v)) * 32 + nh * 16 + half * 8;
      val = *(const uint4*)src;
    }
    unsigned short* dp = (arr == 0 ? sK : sV) + (nh * 72 + pos) * KVSTR + half * 8;
    *(uint4*)dp = val;
  }
  __syncthreads();

  f32x4 acc = {0.f, 0.f, 0.f, 0.f};
  int ocol = wv * 16 + (lane & 15);

  // slot geometry: 8-lane groups; cls = wave parity class; r8 = row-slot
  int cls = wv & 1;                         // wave-uniform
  int nh  = wv >> 1;
  int l8  = lane & 7;
  int r8  = lane >> 3;                      // 0..7
  int ly  = l8 >> 2;
  int lx  = 2 * (l8 & 3) + ((cls + ly) & 1);
  int posb  = ly * 12 + lx;
  int sOrow = cls * 8 + l8;

  // ---- phase 0: rows tq 0..15 (L rows: class-long; S rows: class-short)
  if (fastb) {
    if (cls == 0) attn_ls<0,false>(2*r8,   2*r8+1, true, true, nh, h0,w0,ly,lx,b,qi, posb, sOrow, 0, sK, sV, sO, sRT, sPar);
    else          attn_ls<1,false>(2*r8+1, 2*r8,   true, true, nh, h0,w0,ly,lx,b,qi, posb, sOrow, 0, sK, sV, sO, sRT, sPar);
  } else {
    int tl = (cls == 0) ? 2*r8 : 2*r8+1;
    int ts = (cls == 0) ? 2*r8+1 : 2*r8;
    attn_ls<0,true>(tl, ts, true, true, nh, h0,w0,ly,lx,b,qi, posb, sOrow, 0, sK, sV, sO, sRT, sPar);
  }
  __syncthreads();
  {
    const unsigned short* bcol = wctT + (size_t)ocol * 800 + (lane >> 4) * 8;
    for (int kt = 0; kt < 16; ++kt) {
      h8 bfrag = *(const h8*)(bcol + kt * 32);
      h8 afrag = *(const h8*)&sO[(lane & 15)*OSTRU + kt*32 + (lane >> 4)*8];
      acc = __builtin_amdgcn_mfma_f32_16x16x32_f16(afrag, bfrag, acc, 0, 0, 0);
    }
  }
  __syncthreads();

  // ---- phase 1: rows tq 16..24
  {
    int tqL, tqS; bool wL, wS;
    if (cls == 0) {
      tqL = (r8 < 5) ? 16 + 2*r8 : 16; wL = (r8 < 5);
      tqS = (r8 < 4) ? 17 + 2*r8 : 17; wS = (r8 < 4);
    } else {
      tqL = (r8 < 4) ? 17 + 2*r8 : 17; wL = (r8 < 4);
      tqS = (r8 < 5) ? 16 + 2*r8 : 16; wS = (r8 < 5);
    }
    if (fastb) {
      if (cls == 0) attn_ls<0,false>(tqL, tqS, wL, wS, nh, h0,w0,ly,lx,b,qi, posb, sOrow, 16, sK, sV, sO, sRT, sPar);
      else          attn_ls<1,false>(tqL, tqS, wL, wS, nh, h0,w0,ly,lx,b,qi, posb, sOrow, 16, sK, sV, sO, sRT, sPar);
    } else {
      attn_ls<0,true>(tqL, tqS, wL, wS, nh, h0,w0,ly,lx,b,qi, posb, sOrow, 16, sK, sV, sO, sRT, sPar);
    }
  }
  __syncthreads();
  {
    const unsigned short* bcol = wctT + (size_t)ocol * 800 + 512 + (lane >> 4) * 8;
    for (int kt = 0; kt < 9; ++kt) {
      h8 bfrag = *(const h8*)(bcol + kt * 32);
      h8 afrag = *(const h8*)&sO[(lane & 15)*OSTRU + kt*32 + (lane >> 4)*8];
      acc = __builtin_amdgcn_mfma_f32_16x16x32_f16(afrag, bfrag, acc, 0, 0, 0);
    }
  }
  __syncthreads();

  // epilogue: class-major row -> (ly,lx) remap
  float bco = bc[ocol];
  #pragma unroll
  for (int r2 = 0; r2 < 4; ++r2) {
    int r = (lane >> 4) * 4 + r2;           // 0..15
    int cls2 = r >> 3, i8 = r & 7;
    int ly2 = i8 >> 2, lx2 = 2 * (i8 & 3) + ((cls2 + ly2) & 1);
    int gid = (b << 14) + ((h0 + ly2) << 7) + (w0 + lx2);
    y2[(size_t)gid * 64 + ocol] = acc[r2] + bco;
  }
}

// ---- k3: LN + MLP via MFMA f16 (GELU exact), M0=32 tiles (1024 blocks) --------------
__global__ __launch_bounds__(256) void k_mlp(
    const float* __restrict__ y2, const float* __restrict__ n2w,
    const float* __restrict__ n2b, const unsigned short* __restrict__ w1h,
    const float* __restrict__ b1, const unsigned short* __restrict__ w2h,
    const float* __restrict__ b2, float* __restrict__ out)
{
  __shared__ __align__(16) unsigned short sA[32*72];   // 4608 B
  __shared__ __align__(16) unsigned short sH[32*136];  // 8704 B
  int tid = threadIdx.x;
  int lane = tid & 63, wv = tid >> 6;
  int m0 = blockIdx.x * 32;
  // ---- LN: 8 threads per row (32 rows)
  {
    int r = tid >> 3, qd = tid & 7;
    const float* yp = y2 + (size_t)(m0 + r) * 64 + qd * 8;
    float xv[8];
    float s = 0.f;
    #pragma unroll
    for (int e = 0; e < 2; ++e) {
      float4 t4 = *(const float4*)(yp + e*4);
      xv[4*e] = t4.x; xv[4*e+1] = t4.y; xv[4*e+2] = t4.z; xv[4*e+3] = t4.w;
      s += t4.x + t4.y + t4.z + t4.w;
    }
    s += __shfl_xor(s, 1);
    s += __shfl_xor(s, 2);
    s += __shfl_xor(s, 4);
    float mean = s * (1.f/64.f);
    float v = 0.f;
    #pragma unroll
    for (int e = 0; e < 8; ++e) { float d = xv[e] - mean; v = fmaf(d, d, v); }
    v += __shfl_xor(v, 1);
    v += __shfl_xor(v, 2);
    v += __shfl_xor(v, 4);
    float rs = rsqrtf(v * (1.f/64.f) + 1e-5f);
    #pragma unroll
    for (int u = 0; u < 4; ++u) {
      int c0 = qd*8 + 2*u;
      float h0v = (xv[2*u]   - mean) * rs * n2w[c0]   + n2b[c0];
      float h1v = (xv[2*u+1] - mean) * rs * n2w[c0+1] + n2b[c0+1];
      *(unsigned*)&sA[r*72 + c0] = pkh2(h0v, h1v);
    }
  }
  __syncthreads();
  // ---- GEMM1: [32x64] x W1^T -> [32x128], n-slice 32 per wave
  f32x4 acc1[2][2];
  #pragma unroll
  for (int mt = 0; mt < 2; ++mt)
    #pragma unroll
    for (int nt = 0; nt < 2; ++nt) acc1[mt][nt] = (f32x4){0.f,0.f,0.f,0.f};
  #pragma unroll
  for (int kt = 0; kt < 2; ++kt) {
    #pragma unroll
    for (int nt = 0; nt < 2; ++nt) {
      int ncol = wv*32 + nt*16 + (lane & 15);
      h8 bfrag = *(const h8*)(w1h + ncol*64 + kt*32 + (lane >> 4)*8);
      #pragma unroll
      for (int mt = 0; mt < 2; ++mt) {
        h8 afrag = *(const h8*)&sA[(mt*16 + (lane & 15))*72 + kt*32 + (lane >> 4)*8];
        acc1[mt][nt] = __builtin_amdgcn_mfma_f32_16x16x32_f16(afrag, bfrag, acc1[mt][nt], 0, 0, 0);
      }
    }
  }
  // ---- bias + exact GELU -> sH (fp16)
  #pragma unroll
  for (int nt = 0; nt < 2; ++nt) {
    int ncol = wv*32 + nt*16 + (lane & 15);
    float b1v = b1[ncol];
    #pragma unroll
    for (int mt = 0; mt < 2; ++mt) {
      #pragma unroll
      for (int r2 = 0; r2 < 4; ++r2) {
        int mrow = mt*16 + (lane >> 4)*4 + r2;
        float h = acc1[mt][nt][r2] + b1v;
        float g = 0.5f * h * (1.f + erff(h * 0.70710678118f));
        sH[mrow*136 + ncol] = f2h(g);
      }
    }
  }
  __syncthreads();
  // ---- GEMM2: [32x128] x W2^T -> [32x64], n-slice 16 per wave
  f32x4 acc2[2];
  #pragma unroll
  for (int mt = 0; mt < 2; ++mt) acc2[mt] = (f32x4){0.f,0.f,0.f,0.f};
  int ocol = wv*16 + (lane & 15);
  #pragma unroll
  for (int kt = 0; kt < 4; ++kt) {
    h8 bfrag = *(const h8*)(w2h + ocol*128 + kt*32 + (lane >> 4)*8);
    #pragma unroll
    for (int mt = 0; mt < 2; ++mt) {
      h8 afrag = *(const h8*)&sH[(mt*16 + (lane & 15))*136 + kt*32 + (lane >> 4)*8];
      acc2[mt] = __builtin_amdgcn_mfma_f32_16x16x32_f16(afrag, bfrag, acc2[mt], 0, 0, 0);
    }
  }
  // ---- residual + bias + transpose store
  float b2v = b2[ocol];
  int bb = m0 >> 14;
  #pragma unroll
  for (int mt = 0; mt < 2; ++mt) {
    int mrow = mt*16 + (lane >> 4)*4;
    int l = m0 + mrow;
    const float* yp = y2 + (size_t)l * 64 + ocol;
    float4 o4;
    o4.x = yp[0]   + acc2[mt][0] + b2v;
    o4.y = yp[64]  + acc2[mt][1] + b2v;
    o4.z = yp[128] + acc2[mt][2] + b2v;
    o4.w = yp[192] + acc2[mt][3] + b2v;
    *(float4*)&out[(size_t)bb * 64 * LL + (size_t)ocol * LL + (l - (bb << 14))] = o4;
  }
}

extern "C" void kernel_launch(void* const* d_in, const int* in_sizes, int n_in,
                              void* d_out, int out_size, void* d_ws, size_t ws_size,
                              hipStream_t stream) {
  const float* x         = (const float*)d_in[0];
  const float* qkv_w     = (const float*)d_in[1];
  const float* qkv_b     = (const float*)d_in[2];
  const float* rel_table = (const float*)d_in[3];
  const float* n1w       = (const float*)d_in[4];
  const float* n1b       = (const float*)d_in[5];
  const float* n2w       = (const float*)d_in[6];
  const float* n2b       = (const float*)d_in[7];
  const float* proj_w    = (const float*)d_in[8];
  const float* proj_b    = (const float*)d_in[9];
  const float* fw        = (const float*)d_in[10];
  const float* fb        = (const float*)d_in[11];
  const float* w1        = (const float*)d_in[12];
  const float* b1        = (const float*)d_in[13];
  const float* w2        = (const float*)d_in[14];
  const float* b2        = (const float*)d_in[15];

  char* ws = (char*)d_ws;
  unsigned short* q    = (unsigned short*)(ws);                    // BL*32 fp16 = 2MB
  unsigned short* k    = (unsigned short*)(ws + 2097152);          // 2MB
  unsigned short* v    = (unsigned short*)(ws + 4194304);          // 2MB
  float*          y2   = (float*)(ws + 6291456);                   // BL*64 f32 = 8MB
  unsigned short* wctT = (unsigned short*)(ws + 14680064);         // 64*800 fp16
  float*          bc   = (float*)(ws + 14782464);                  // 64 f32
  unsigned short* w1h  = (unsigned short*)(ws + 14782720);         // 8192 fp16
  unsigned short* w2h  = (unsigned short*)(ws + 14799104);         // 8192 fp16
  float* out = (float*)d_out;

  k_combine<<<203, 256, 0, stream>>>(proj_w, proj_b, fw, fb, w1, w2, wctT, bc, w1h, w2h);
  k_ln_qkv<<<dim3(BL/128, 3), 128, 0, stream>>>(x, qkv_w, qkv_b, n1w, n1b, q, k, v);
  k_attn<<<dim3(WW/TW, HH/TH, 2), 256, 0, stream>>>(q, k, v, rel_table, wctT, bc, y2);
  k_mlp<<<BL/32, 256, 0, stream>>>(y2, n2w, n2b, w1h, b1, w2h, b2, out);
}